// Round 1
// baseline (79.779 us; speedup 1.0000x reference)
//
#include <hip/hip_runtime.h>
#include <cfloat>

// Chamfer L1, pred [B,N,3], gt [B,M,3] fp32, N==M==4096, B==4.
// Kernel 1: per (dir, b, query-chunk, target-chunk) block computes each query's
//           min over the staged target chunk; coalesced store of the partial
//           min to ws[mc][dir][b][n]. No atomics, no init pass.
//   R1 changes vs 77.7us baseline:
//     PTS 4->8 : 48 VALU per ds_read_b128 -> LDS pipe at 50%, VALU sole bottleneck
//     MC 256->64: grid 512->1024 blocks -> 4 blocks/CU, 4 waves/SIMD latency hiding
// Kernel 2: min-reduce over the 64 target-chunks per query, scale, block-sum,
//           one float atomicAdd per block into d_out (memset to 0 first).

constexpr int TPB = 256;
constexpr int PTS = 8;            // query points per thread (ILP: 48 VALU per LDS read)
constexpr int NC  = TPB * PTS;    // 2048 queries per block
constexpr int MC  = 64;           // targets staged in LDS per block

__global__ __launch_bounds__(TPB) void chamfer_partial_kernel(
    const float* __restrict__ pred, const float* __restrict__ gt,
    float* __restrict__ partial, int B, int N, int M) {
    const int dir = blockIdx.z;
    const int b   = blockIdx.y;
    const float* q = dir ? gt   : pred;
    const float* t = dir ? pred : gt;
    const int Nq   = dir ? M : N;
    const int Nt   = dir ? N : M;
    const int nchunks = Nq / NC;              // 2
    const int nc = blockIdx.x % nchunks;
    const int mc = blockIdx.x / nchunks;      // 0..Nt/MC-1 (63)

    __shared__ float4 lds4[MC];               // w unused; 1 KB

    // Stage target chunk (64 pts x 12 B) into LDS as padded float4.
    const float* tbase = t + ((size_t)b * Nt + (size_t)mc * MC) * 3;
    for (int i = threadIdx.x; i < MC * 3; i += TPB) {
        ((float*)&lds4[i / 3])[i % 3] = tbase[i];
    }
    __syncthreads();

    // 8 query points per thread, in registers.
    const float* qb = q + (size_t)b * Nq * 3;
    float px[PTS], py[PTS], pz[PTS], mn[PTS];
#pragma unroll
    for (int i = 0; i < PTS; ++i) {
        const int n = nc * NC + threadIdx.x + i * TPB;
        px[i] = qb[n * 3 + 0];
        py[i] = qb[n * 3 + 1];
        pz[i] = qb[n * 3 + 2];
        mn[i] = FLT_MAX;
    }

#pragma unroll 8
    for (int j = 0; j < MC; ++j) {
        float4 g = lds4[j];   // broadcast ds_read_b128 — all lanes same addr
#pragma unroll
        for (int i = 0; i < PTS; ++i) {
            float d = fabsf(px[i] - g.x) + fabsf(py[i] - g.y) + fabsf(pz[i] - g.z);
            mn[i] = fminf(mn[i], d);
        }
    }

    // partial[mc][dir][b][n] — coalesced stores (N==M assumed for stride).
    float* outp = partial + (((size_t)mc * 2 + dir) * B + b) * N + nc * NC + threadIdx.x;
#pragma unroll
    for (int i = 0; i < PTS; ++i) outp[i * TPB] = mn[i];
}

__global__ __launch_bounds__(256) void chamfer_reduce_kernel(
    const float* __restrict__ partial, float* __restrict__ out,
    int Q, float inv) {
    const int qidx = blockIdx.x * 256 + threadIdx.x;
    float mn = FLT_MAX;
#pragma unroll
    for (int mc = 0; mc < 64; ++mc)   // nmc == 64 for N==M==4096, MC==64
        mn = fminf(mn, partial[(size_t)mc * Q + qidx]);
    float v = mn * inv;

    // wave-64 shuffle reduce, then cross-wave via LDS
    for (int off = 32; off > 0; off >>= 1) v += __shfl_down(v, off, 64);
    __shared__ float red[4];
    const int lane = threadIdx.x & 63, w = threadIdx.x >> 6;
    if (lane == 0) red[w] = v;
    __syncthreads();
    if (threadIdx.x == 0)
        atomicAdd(out, red[0] + red[1] + red[2] + red[3]);
}

extern "C" void kernel_launch(void* const* d_in, const int* in_sizes, int n_in,
                              void* d_out, int out_size, void* d_ws, size_t ws_size,
                              hipStream_t stream) {
    const float* pred = (const float*)d_in[0];
    const float* gt   = (const float*)d_in[1];
    float* out = (float*)d_out;

    const int B = 4;
    const int N = in_sizes[0] / (B * 3);   // 4096
    const int M = in_sizes[1] / (B * 3);   // 4096

    float* partial = (float*)d_ws;          // [64][2][B][N] floats = 8 MB
    const int nmc = M / MC;                 // 64
    const int Q = 2 * B * N;                // 32768

    hipMemsetAsync(out, 0, sizeof(float), stream);

    dim3 grid((N / NC) * nmc, B, 2);        // 128 x 4 x 2 = 1024 blocks
    chamfer_partial_kernel<<<grid, TPB, 0, stream>>>(pred, gt, partial, B, N, M);

    // mean scale: 1/(B*N) for dir0, 1/(B*M) for dir1 — equal since N==M.
    chamfer_reduce_kernel<<<Q / 256, 256, 0, stream>>>(
        partial, out, Q, 1.0f / (float)(B * N));
}

// Round 2
// 79.145 us; speedup vs baseline: 1.0080x; 1.0080x over previous
//
#include <hip/hip_runtime.h>
#include <cfloat>

// Chamfer L1, pred [B,N,3], gt [B,M,3] fp32, N==M==4096, B==4.
// R2: revert to R0 geometry (PTS=4, MC=256, 512 blocks — best measured; R1
//     showed the kernel is VALU-bound, occupancy changes neutral, and total
//     time tracks workspace bytes). Replace the 2MB partial buffer + min-pass
//     with a 128KB uint atomicMin array (L1 dist >= 0 -> float bits monotone
//     as uint). Pair targets so the min chain can fuse to v_min3_f32.
// Kernel 1: per (dir, b, query-chunk, target-chunk) block: per-query min over
//           staged target chunk; one atomicMin(uint) per query per chunk.
// Kernel 2: read 32768 uints, scale, block-sum, one atomicAdd per block.

constexpr int TPB = 256;
constexpr int PTS = 4;            // query points per thread
constexpr int NC  = TPB * PTS;    // 1024 queries per block
constexpr int MC  = 256;          // targets staged in LDS per block

__global__ __launch_bounds__(TPB) void chamfer_partial_kernel(
    const float* __restrict__ pred, const float* __restrict__ gt,
    unsigned* __restrict__ wsmin, int B, int N, int M) {
    const int dir = blockIdx.z;
    const int b   = blockIdx.y;
    const float* q = dir ? gt   : pred;
    const float* t = dir ? pred : gt;
    const int Nq   = dir ? M : N;
    const int Nt   = dir ? N : M;
    const int nchunks = Nq / NC;              // 4
    const int nc = blockIdx.x % nchunks;
    const int mc = blockIdx.x / nchunks;      // 0..Nt/MC-1 (15)

    __shared__ float4 lds4[MC];               // w unused; 4 KB

    // Stage target chunk (256 pts x 12 B) into LDS as padded float4.
    const float* tbase = t + ((size_t)b * Nt + (size_t)mc * MC) * 3;
    for (int i = threadIdx.x; i < MC * 3; i += TPB) {
        ((float*)&lds4[i / 3])[i % 3] = tbase[i];
    }
    __syncthreads();

    // 4 query points per thread, in registers.
    const float* qb = q + (size_t)b * Nq * 3;
    float px[PTS], py[PTS], pz[PTS], mn[PTS];
    int n[PTS];
#pragma unroll
    for (int i = 0; i < PTS; ++i) {
        n[i] = nc * NC + threadIdx.x + i * TPB;
        px[i] = qb[n[i] * 3 + 0];
        py[i] = qb[n[i] * 3 + 1];
        pz[i] = qb[n[i] * 3 + 2];
        mn[i] = FLT_MAX;
    }

    // Pairs of targets: d0,d1 then a fmin(fmin) chain -> v_min3_f32 candidate.
#pragma unroll 4
    for (int j = 0; j < MC; j += 2) {
        float4 g0 = lds4[j];      // broadcast ds_read_b128 — all lanes same addr
        float4 g1 = lds4[j + 1];
#pragma unroll
        for (int i = 0; i < PTS; ++i) {
            float d0 = fabsf(px[i] - g0.x) + fabsf(py[i] - g0.y) + fabsf(pz[i] - g0.z);
            float d1 = fabsf(px[i] - g1.x) + fabsf(py[i] - g1.y) + fabsf(pz[i] - g1.z);
            mn[i] = fminf(mn[i], fminf(d0, d1));
        }
    }

    // One atomicMin per query per target-chunk into L2-resident 128KB array.
    // d >= 0 so float bits compare correctly as uint.
    unsigned* outp = wsmin + ((size_t)dir * B + b) * N;
#pragma unroll
    for (int i = 0; i < PTS; ++i)
        atomicMin(&outp[n[i]], __float_as_uint(mn[i]));
}

__global__ __launch_bounds__(256) void chamfer_reduce_kernel(
    const unsigned* __restrict__ wsmin, float* __restrict__ out, float inv) {
    const int qidx = blockIdx.x * 256 + threadIdx.x;
    float v = __uint_as_float(wsmin[qidx]) * inv;

    // wave-64 shuffle reduce, then cross-wave via LDS
    for (int off = 32; off > 0; off >>= 1) v += __shfl_down(v, off, 64);
    __shared__ float red[4];
    const int lane = threadIdx.x & 63, w = threadIdx.x >> 6;
    if (lane == 0) red[w] = v;
    __syncthreads();
    if (threadIdx.x == 0)
        atomicAdd(out, red[0] + red[1] + red[2] + red[3]);
}

extern "C" void kernel_launch(void* const* d_in, const int* in_sizes, int n_in,
                              void* d_out, int out_size, void* d_ws, size_t ws_size,
                              hipStream_t stream) {
    const float* pred = (const float*)d_in[0];
    const float* gt   = (const float*)d_in[1];
    float* out = (float*)d_out;

    const int B = 4;
    const int N = in_sizes[0] / (B * 3);   // 4096
    const int M = in_sizes[1] / (B * 3);   // 4096

    unsigned* wsmin = (unsigned*)d_ws;      // [2][B][N] uints = 128 KB (L2-resident)
    const int nmc = M / MC;                 // 16
    const int Q = 2 * B * N;                // 32768

    hipMemsetAsync(out, 0, sizeof(float), stream);
    hipMemsetAsync(wsmin, 0xFF, (size_t)Q * sizeof(unsigned), stream);  // uint max

    dim3 grid((N / NC) * nmc, B, 2);        // 64 x 4 x 2 = 512 blocks
    chamfer_partial_kernel<<<grid, TPB, 0, stream>>>(pred, gt, wsmin, B, N, M);

    // mean scale: 1/(B*N) for dir0, 1/(B*M) for dir1 — equal since N==M.
    chamfer_reduce_kernel<<<Q / 256, 256, 0, stream>>>(
        wsmin, out, 1.0f / (float)(B * N));
}